// Round 8
// baseline (104.043 us; speedup 1.0000x reference)
//
#include <hip/hip_runtime.h>

#define D 256
#define LKEYS 128
#define NGROUP 1024
#define NQ 4096

// ws layout (float offsets)
#define MMAT_OFF 0
#define RVEC_OFF (D * D)
#define U_OFF    (RVEC_OFF + D)
#define PART_OFF (U_OFF + NQ * D)
#define PART_STRIDE 260                     // acc[256], m, su, pad2
#define WS_FLOATS (PART_OFF + 2 * NQ * PART_STRIDE)   // ~13 MB

#define DOT4(a, b) ((a).x*(b).x + (a).y*(b).y + (a).z*(b).z + (a).w*(b).w)

// ---------------------------------------------------------------------------
// prep: M = Wq @ Wk^T, r = bq @ Wk^T. bk dropped (softmax-invariant).
// ---------------------------------------------------------------------------
__global__ __launch_bounds__(256) void prep_kernel(
    const float* __restrict__ Wq, const float* __restrict__ Wk,
    const float* __restrict__ bq, float* __restrict__ Mmat,
    float* __restrict__ rvec)
{
    __shared__ float wq_s[32][65];
    __shared__ float wk_s[32][65];
    __shared__ float bq_s[64];
    const int t  = threadIdx.x;
    const int a0 = (int)(blockIdx.x >> 3) * 32;
    const int b0 = (int)(blockIdx.x & 7) * 32;
    const int ai = t >> 4;
    const int bj = t & 15;
    float acc00 = 0.f, acc01 = 0.f, acc10 = 0.f, acc11 = 0.f;
    float racc = 0.f;
    for (int z0 = 0; z0 < D; z0 += 64) {
        __syncthreads();
        #pragma unroll
        for (int i = 0; i < 2; ++i) {
            const int f4i = t + 256 * i;
            const int row = f4i >> 4;
            const int c   = (f4i & 15) * 4;
            float4 aa = *(const float4*)&Wq[(size_t)(a0 + row) * D + z0 + c];
            wq_s[row][c] = aa.x; wq_s[row][c+1] = aa.y; wq_s[row][c+2] = aa.z; wq_s[row][c+3] = aa.w;
            float4 bb = *(const float4*)&Wk[(size_t)(b0 + row) * D + z0 + c];
            wk_s[row][c] = bb.x; wk_s[row][c+1] = bb.y; wk_s[row][c+2] = bb.z; wk_s[row][c+3] = bb.w;
        }
        if (t < 64) bq_s[t] = bq[z0 + t];
        __syncthreads();
        #pragma unroll 8
        for (int z = 0; z < 64; ++z) {
            const float wq0 = wq_s[ai][z];
            const float wq1 = wq_s[ai + 16][z];
            const float wk0 = wk_s[bj][z];
            const float wk1 = wk_s[bj + 16][z];
            acc00 += wq0 * wk0; acc01 += wq0 * wk1;
            acc10 += wq1 * wk0; acc11 += wq1 * wk1;
        }
        if (a0 == 0 && t < 32) {
            #pragma unroll 8
            for (int z = 0; z < 64; ++z) racc += bq_s[z] * wk_s[t][z];
        }
    }
    Mmat[(size_t)(a0 + ai)      * D + b0 + bj]      = acc00;
    Mmat[(size_t)(a0 + ai)      * D + b0 + bj + 16] = acc01;
    Mmat[(size_t)(a0 + ai + 16) * D + b0 + bj]      = acc10;
    Mmat[(size_t)(a0 + ai + 16) * D + b0 + bj + 16] = acc11;
    if (a0 == 0 && t < 32) rvec[b0 + t] = racc;
}

// ---------------------------------------------------------------------------
// u GEMM: u = (q @ M + r) * (1/sqrt(256)). 256 blocks x 16 queries.
// ---------------------------------------------------------------------------
__global__ __launch_bounds__(256) void u_gemm_kernel(
    const float* __restrict__ q, const float* __restrict__ Mmat,
    const float* __restrict__ rvec, float* __restrict__ uout)
{
    __shared__ float q_s[16][D];
    const int b = blockIdx.x, t = threadIdx.x, lane = t & 63, w = t >> 6;
    {
        const float4* qg = (const float4*)(q + (size_t)b * 16 * D);
        float4* qs4 = (float4*)q_s;
        #pragma unroll
        for (int i = 0; i < 4; ++i) qs4[t + 256 * i] = qg[t + 256 * i];
    }
    __syncthreads();

    const float4* M4 = (const float4*)Mmat;
    const int r0 = w * 4;
    float4 a0 = {0,0,0,0}, a1 = {0,0,0,0}, a2 = {0,0,0,0}, a3 = {0,0,0,0};
    #pragma unroll 4
    for (int kk = 0; kk < D; ++kk) {
        const float4 m4 = M4[kk * 64 + lane];
        const float qa = q_s[r0 + 0][kk], qb = q_s[r0 + 1][kk];
        const float qc = q_s[r0 + 2][kk], qd = q_s[r0 + 3][kk];
        a0.x += qa*m4.x; a0.y += qa*m4.y; a0.z += qa*m4.z; a0.w += qa*m4.w;
        a1.x += qb*m4.x; a1.y += qb*m4.y; a1.z += qb*m4.z; a1.w += qb*m4.w;
        a2.x += qc*m4.x; a2.y += qc*m4.y; a2.z += qc*m4.z; a2.w += qc*m4.w;
        a3.x += qd*m4.x; a3.y += qd*m4.y; a3.z += qd*m4.z; a3.w += qd*m4.w;
    }
    const float4 r4 = ((const float4*)rvec)[lane];
    float4* U4 = (float4*)uout;
    float4 o;
    o.x=(a0.x+r4.x)*0.0625f; o.y=(a0.y+r4.y)*0.0625f; o.z=(a0.z+r4.z)*0.0625f; o.w=(a0.w+r4.w)*0.0625f;
    U4[((size_t)b * 16 + r0 + 0) * 64 + lane] = o;
    o.x=(a1.x+r4.x)*0.0625f; o.y=(a1.y+r4.y)*0.0625f; o.z=(a1.z+r4.z)*0.0625f; o.w=(a1.w+r4.w)*0.0625f;
    U4[((size_t)b * 16 + r0 + 1) * 64 + lane] = o;
    o.x=(a2.x+r4.x)*0.0625f; o.y=(a2.y+r4.y)*0.0625f; o.z=(a2.z+r4.z)*0.0625f; o.w=(a2.w+r4.w)*0.0625f;
    U4[((size_t)b * 16 + r0 + 2) * 64 + lane] = o;
    o.x=(a3.x+r4.x)*0.0625f; o.y=(a3.y+r4.y)*0.0625f; o.z=(a3.z+r4.z)*0.0625f; o.w=(a3.w+r4.w)*0.0625f;
    U4[((size_t)b * 16 + r0 + 3) * 64 + lane] = o;
}

// ---------------------------------------------------------------------------
// attn5: max-occupancy half-group kernel. Grid 2048 = (group g, half h).
// Block handles 64 keys; wave w: scores for keys [16w,16w+16) (tree-reduce),
// partial softmax for query w over the 64 keys, then v rows [16w,16w+16)
// for ALL 4 queries (transposed p broadcast), LDS combine, partial to ws.
// __launch_bounds__(256,8): VGPR<=64 -> 8 blocks/CU = 32 waves/CU.
// Per-wave latency steps: 4 k-batches + 2 v-batches.
// ---------------------------------------------------------------------------
__global__ __launch_bounds__(256, 8) void attn5_kernel(
    const float* __restrict__ k, const float* __restrict__ v,
    const int* __restrict__ m, const float* __restrict__ uws,
    float* __restrict__ part)
{
    const int b = blockIdx.x;
    const int g = b >> 1, h = b & 1;
    const int t = threadIdx.x, lane = t & 63, w = t >> 6;

    __shared__ float4 part_s[4][4][64];   // 16 KB [src_wave][query][c4]
    __shared__ float  p_t[64][4];         //  1 KB [local_key][query]

    const float4* U4 = (const float4*)(uws + (size_t)g * 4 * D);
    const float4 u0 = U4[0 * 64 + lane];
    const float4 u1 = U4[1 * 64 + lane];
    const float4 u2 = U4[2 * 64 + lane];
    const float4 u3 = U4[3 * 64 + lane];

    const int kofs = h * 64;
    const int mk = m[(size_t)g * LKEYS + kofs + lane];   // one mask/lane
    const unsigned long long bal = __ballot(mk != 0);    // bit l = local key l

    const float4* kg = (const float4*)(k + ((size_t)g * LKEYS + kofs) * D);
    const float4* vg = (const float4*)(v + ((size_t)g * LKEYS + kofs) * D);

    // ---- scores: wave w local keys [16w,16w+16), 4 batches of 4 ----
    #pragma unroll
    for (int it = 0; it < 4; ++it) {
        const int kb = w * 16 + it * 4;
        const float4 ka0 = kg[(kb + 0) * 64 + lane];
        const float4 ka1 = kg[(kb + 1) * 64 + lane];
        const float4 ka2 = kg[(kb + 2) * 64 + lane];
        const float4 ka3 = kg[(kb + 3) * 64 + lane];

        float v16[16];   // v16[key*4 + q]
        v16[ 0]=DOT4(ka0,u0); v16[ 1]=DOT4(ka0,u1); v16[ 2]=DOT4(ka0,u2); v16[ 3]=DOT4(ka0,u3);
        v16[ 4]=DOT4(ka1,u0); v16[ 5]=DOT4(ka1,u1); v16[ 6]=DOT4(ka1,u2); v16[ 7]=DOT4(ka1,u3);
        v16[ 8]=DOT4(ka2,u0); v16[ 9]=DOT4(ka2,u1); v16[10]=DOT4(ka2,u2); v16[11]=DOT4(ka2,u3);
        v16[12]=DOT4(ka3,u0); v16[13]=DOT4(ka3,u1); v16[14]=DOT4(ka3,u2); v16[15]=DOT4(ka3,u3);

        // batched tree reduce across 64 lanes: 16 -> 8 -> 4 -> 2 -> 1
        float v8[8];
        { const int hb = lane & 1;
          #pragma unroll
          for (int i = 0; i < 8; ++i) {
              const float keep = hb ? v16[8 + i] : v16[i];
              const float send = hb ? v16[i]     : v16[8 + i];
              v8[i] = keep + __shfl_xor(send, 1);
          } }
        float v4a[4];
        { const int hb = (lane >> 1) & 1;
          #pragma unroll
          for (int i = 0; i < 4; ++i) {
              const float keep = hb ? v8[4 + i] : v8[i];
              const float send = hb ? v8[i]     : v8[4 + i];
              v4a[i] = keep + __shfl_xor(send, 2);
          } }
        float v2a[2];
        { const int hb = (lane >> 2) & 1;
          #pragma unroll
          for (int i = 0; i < 2; ++i) {
              const float keep = hb ? v4a[2 + i] : v4a[i];
              const float send = hb ? v4a[i]     : v4a[2 + i];
              v2a[i] = keep + __shfl_xor(send, 4);
          } }
        float v1;
        { const int hb = (lane >> 3) & 1;
          const float keep = hb ? v2a[1] : v2a[0];
          const float send = hb ? v2a[0] : v2a[1];
          v1 = keep + __shfl_xor(send, 8); }
        v1 += __shfl_xor(v1, 16);
        v1 += __shfl_xor(v1, 32);

        if (lane < 16) {
            // lane bits -> value index i; i = local_key*4 + query
            const int i  = ((lane & 1) << 3) | ((lane & 2) << 1) | ((lane & 4) >> 1) | ((lane & 8) >> 3);
            const int kl = kb + (i >> 2);
            p_t[kl][i & 3] = ((bal >> kl) & 1ull) ? v1 : -1e30f;
        }
    }
    __syncthreads();

    // ---- partial softmax: wave w = query w over the 64 local keys ----
    float m_loc, su;
    {
        const float s = p_t[lane][w];
        float mx = s;
        #pragma unroll
        for (int off = 32; off > 0; off >>= 1) mx = fmaxf(mx, __shfl_xor(mx, off));
        const bool valid = (bal >> lane) & 1ull;
        const float e = valid ? __expf(s - mx) : 0.f;   // all-masked half -> su=0
        float ss = e;
        #pragma unroll
        for (int off = 32; off > 0; off >>= 1) ss += __shfl_xor(ss, off);
        p_t[lane][w] = e;     // unnormalized; column w for all key rows
        m_loc = mx; su = ss;
    }
    __syncthreads();

    // ---- v: wave w rows [16w,16w+16) for ALL 4 queries, 2 batches of 8 ----
    float4 a0 = {0,0,0,0}, a1 = {0,0,0,0}, a2 = {0,0,0,0}, a3 = {0,0,0,0};
    #pragma unroll
    for (int it = 0; it < 2; ++it) {
        const int base = w * 16 + it * 8;
        float4 va[8];
        #pragma unroll
        for (int j = 0; j < 8; ++j) va[j] = vg[(base + j) * 64 + lane];
        #pragma unroll
        for (int j = 0; j < 8; ++j) {
            const float4 pr = *(const float4*)&p_t[base + j][0];   // broadcast
            const float4 vv = va[j];
            a0.x += pr.x*vv.x; a0.y += pr.x*vv.y; a0.z += pr.x*vv.z; a0.w += pr.x*vv.w;
            a1.x += pr.y*vv.x; a1.y += pr.y*vv.y; a1.z += pr.y*vv.z; a1.w += pr.y*vv.w;
            a2.x += pr.z*vv.x; a2.y += pr.z*vv.y; a2.z += pr.z*vv.z; a2.w += pr.z*vv.w;
            a3.x += pr.w*vv.x; a3.y += pr.w*vv.y; a3.z += pr.w*vv.z; a3.w += pr.w*vv.w;
        }
    }

    // ---- LDS combine across waves; wave w finalizes query w ----
    part_s[w][0][lane] = a0; part_s[w][1][lane] = a1;
    part_s[w][2][lane] = a2; part_s[w][3][lane] = a3;
    __syncthreads();
    {
        const float4 r0 = part_s[0][w][lane];
        const float4 r1 = part_s[1][w][lane];
        const float4 r2 = part_s[2][w][lane];
        const float4 r3 = part_s[3][w][lane];
        float4 o;
        o.x = r0.x + r1.x + r2.x + r3.x;
        o.y = r0.y + r1.y + r2.y + r3.y;
        o.z = r0.z + r1.z + r2.z + r3.z;
        o.w = r0.w + r1.w + r2.w + r3.w;
        float* pb = part + ((size_t)h * NQ + (size_t)g * 4 + w) * PART_STRIDE;
        ((float4*)pb)[lane] = o;
        if (lane == 0) { pb[256] = m_loc; pb[257] = su; }
    }
}

// ---------------------------------------------------------------------------
// combine: out[i] = (fA*accA + fB*accB) / (fA*suA + fB*suB)   [R4, proven]
// ---------------------------------------------------------------------------
__global__ __launch_bounds__(256) void combine_kernel(
    const float* __restrict__ part, float* __restrict__ out)
{
    const int b = blockIdx.x, t = threadIdx.x, lane = t & 63, w = t >> 6;
    const int i = b * 4 + w;
    const float* pA = part + (size_t)i * PART_STRIDE;
    const float* pB = part + ((size_t)NQ + i) * PART_STRIDE;
    const float mA = pA[256], suA = pA[257];
    const float mB = pB[256], suB = pB[257];
    const float Mx = fmaxf(mA, mB);
    const float fA = __expf(mA - Mx);      // all-masked half: exp(-huge)=0
    const float fB = __expf(mB - Mx);
    const float inv = 1.0f / (fA * suA + fB * suB);
    const float4 aA = ((const float4*)pA)[lane];
    const float4 aB = ((const float4*)pB)[lane];
    float4 o;
    o.x = (fA*aA.x + fB*aB.x) * inv;
    o.y = (fA*aA.y + fB*aB.y) * inv;
    o.z = (fA*aA.z + fB*aB.z) * inv;
    o.w = (fA*aA.w + fB*aB.w) * inv;
    ((float4*)out)[(size_t)i * 64 + lane] = o;
}

// ---------------------------------------------------------------------------
// Fallback (ws too small): proven R2 all-in-one kernel.
// ---------------------------------------------------------------------------
__global__ __launch_bounds__(256) void attn_kernel(
    const float* __restrict__ q, const float* __restrict__ k,
    const float* __restrict__ v, const int* __restrict__ m,
    const float* __restrict__ Mmat, const float* __restrict__ rvec,
    float* __restrict__ out)
{
    const int g    = blockIdx.x;
    const int t    = threadIdx.x;
    const int lane = t & 63;
    const int w    = t >> 6;

    __shared__ float  q_s[4][D];
    __shared__ float4 part_s[4][4][64];
    __shared__ float4 u_s4[4][64];
    __shared__ float  p_s[4][LKEYS];
    __shared__ int    m_s[LKEYS];

    {
        const float4* qg = (const float4*)(q + (size_t)g * 4 * D);
        ((float4*)q_s)[t] = qg[t];
    }
    if (t < LKEYS) m_s[t] = m[(size_t)g * LKEYS + t];
    __syncthreads();
    {
        const float4* M4 = (const float4*)Mmat;
        float4 p0 = {0,0,0,0}, p1 = {0,0,0,0}, p2 = {0,0,0,0}, p3 = {0,0,0,0};
        const int base = w * 64;
        #pragma unroll 4
        for (int dd = 0; dd < 64; ++dd) {
            const int a = base + dd;
            const float4 m4 = M4[a * 64 + lane];
            const float q0 = q_s[0][a], q1 = q_s[1][a], q2 = q_s[2][a], q3 = q_s[3][a];
            p0.x += q0*m4.x; p0.y += q0*m4.y; p0.z += q0*m4.z; p0.w += q0*m4.w;
            p1.x += q1*m4.x; p1.y += q1*m4.y; p1.z += q1*m4.z; p1.w += q1*m4.w;
            p2.x += q2*m4.x; p2.y += q2*m4.y; p2.z += q2*m4.z; p2.w += q2*m4.w;
            p3.x += q3*m4.x; p3.y += q3*m4.y; p3.z += q3*m4.z; p3.w += q3*m4.w;
        }
        part_s[w][0][lane] = p0; part_s[w][1][lane] = p1;
        part_s[w][2][lane] = p2; part_s[w][3][lane] = p3;
    }
    __syncthreads();
    {
        float4 acc = ((const float4*)rvec)[lane];
        const float4 a0 = part_s[0][w][lane], a1 = part_s[1][w][lane];
        const float4 a2 = part_s[2][w][lane], a3 = part_s[3][w][lane];
        acc.x += a0.x + a1.x + a2.x + a3.x;
        acc.y += a0.y + a1.y + a2.y + a3.y;
        acc.z += a0.z + a1.z + a2.z + a3.z;
        acc.w += a0.w + a1.w + a2.w + a3.w;
        u_s4[w][lane] = acc;
    }
    __syncthreads();

    const float4 u0 = u_s4[0][lane], u1 = u_s4[1][lane];
    const float4 u2 = u_s4[2][lane], u3 = u_s4[3][lane];
    {
        const float4* kg = (const float4*)(k + (size_t)g * LKEYS * D);
        auto reduce_qt = [&](float d0, float d1, float d2, float d3) -> float {
            float keepA = (lane & 1) ? d1 : d0;
            float sendA = (lane & 1) ? d0 : d1;
            keepA += __shfl_xor(sendA, 1);
            float keepB = (lane & 1) ? d3 : d2;
            float sendB = (lane & 1) ? d2 : d3;
            keepB += __shfl_xor(sendB, 1);
            float keep = (lane & 2) ? keepB : keepA;
            float send = (lane & 2) ? keepA : keepB;
            keep += __shfl_xor(send, 2);
            keep += __shfl_xor(keep, 4);
            keep += __shfl_xor(keep, 8);
            keep += __shfl_xor(keep, 16);
            keep += __shfl_xor(keep, 32);
            return keep;
        };
        const int l0 = w * 32;
        for (int kk = 0; kk < 32; kk += 4) {
            const int l = l0 + kk;
            const float4 kA = kg[(l + 0) * 64 + lane];
            const float4 kB = kg[(l + 1) * 64 + lane];
            const float4 kC = kg[(l + 2) * 64 + lane];
            const float4 kD = kg[(l + 3) * 64 + lane];
            float dA0 = DOT4(kA,u0), dA1 = DOT4(kA,u1), dA2 = DOT4(kA,u2), dA3 = DOT4(kA,u3);
            float dB0 = DOT4(kB,u0), dB1 = DOT4(kB,u1), dB2 = DOT4(kB,u2), dB3 = DOT4(kB,u3);
            float dC0 = DOT4(kC,u0), dC1 = DOT4(kC,u1), dC2 = DOT4(kC,u2), dC3 = DOT4(kC,u3);
            float dD0 = DOT4(kD,u0), dD1 = DOT4(kD,u1), dD2 = DOT4(kD,u2), dD3 = DOT4(kD,u3);
            const float rA = reduce_qt(dA0, dA1, dA2, dA3);
            const float rB = reduce_qt(dB0, dB1, dB2, dB3);
            const float rC = reduce_qt(dC0, dC1, dC2, dC3);
            const float rD = reduce_qt(dD0, dD1, dD2, dD3);
            if (lane < 4) {
                p_s[lane][l + 0] = m_s[l + 0] ? rA * 0.0625f : -1e30f;
                p_s[lane][l + 1] = m_s[l + 1] ? rB * 0.0625f : -1e30f;
                p_s[lane][l + 2] = m_s[l + 2] ? rC * 0.0625f : -1e30f;
                p_s[lane][l + 3] = m_s[l + 3] ? rD * 0.0625f : -1e30f;
            }
        }
    }
    __syncthreads();
    {
        const float v0 = p_s[w][lane];
        const float v1 = p_s[w][lane + 64];
        float mx = fmaxf(v0, v1);
        #pragma unroll
        for (int off = 32; off > 0; off >>= 1) mx = fmaxf(mx, __shfl_xor(mx, off));
        const float e0 = __expf(v0 - mx);
        const float e1 = __expf(v1 - mx);
        float sm = e0 + e1;
        #pragma unroll
        for (int off = 32; off > 0; off >>= 1) sm += __shfl_xor(sm, off);
        const float inv = 1.0f / sm;
        p_s[w][lane]      = e0 * inv;
        p_s[w][lane + 64] = e1 * inv;
    }
    {
        const float4* vg = (const float4*)(v + (size_t)g * LKEYS * D);
        float4 acc = {0,0,0,0};
        #pragma unroll 8
        for (int l = 0; l < LKEYS; ++l) {
            const float pw = p_s[w][l];
            const float4 vv = vg[l * 64 + lane];
            acc.x += pw * vv.x; acc.y += pw * vv.y;
            acc.z += pw * vv.z; acc.w += pw * vv.w;
        }
        float4* og = (float4*)(out + ((size_t)g * 4 + w) * D);
        og[lane] = acc;
    }
}

extern "C" void kernel_launch(void* const* d_in, const int* in_sizes, int n_in,
                              void* d_out, int out_size, void* d_ws, size_t ws_size,
                              hipStream_t stream) {
    // inputs: nq(0), q(1), k(2), v(3), m(4), Wq(5), bq(6), Wk(7), bk(8)
    const float* q  = (const float*)d_in[1];
    const float* k  = (const float*)d_in[2];
    const float* v  = (const float*)d_in[3];
    const int*   m  = (const int*)  d_in[4];
    const float* Wq = (const float*)d_in[5];
    const float* bq = (const float*)d_in[6];
    const float* Wk = (const float*)d_in[7];

    float* ws = (float*)d_ws;
    prep_kernel<<<64, 256, 0, stream>>>(Wq, Wk, bq, ws + MMAT_OFF, ws + RVEC_OFF);

    if (ws_size >= (size_t)WS_FLOATS * sizeof(float)) {
        u_gemm_kernel<<<NQ / 16, 256, 0, stream>>>(q, ws + MMAT_OFF, ws + RVEC_OFF, ws + U_OFF);
        attn5_kernel<<<NGROUP * 2, 256, 0, stream>>>(k, v, m, ws + U_OFF, ws + PART_OFF);
        combine_kernel<<<NGROUP, 256, 0, stream>>>(ws + PART_OFF, (float*)d_out);
    } else {
        attn_kernel<<<NGROUP, 256, 0, stream>>>(q, k, v, m, ws + MMAT_OFF, ws + RVEC_OFF,
                                                (float*)d_out);
    }
}

// Round 9
// 69.463 us; speedup vs baseline: 1.4978x; 1.4978x over previous
//
#include <hip/hip_runtime.h>

#define D 256
#define LKEYS 128
#define NGROUP 1024

// ws layout (float offsets)
#define MMAT_OFF 0
#define RVEC_OFF (D * D)
#define WS_FLOATS (RVEC_OFF + D)            // 257 KB

#define DOT4(a, b) ((a).x*(b).x + (a).y*(b).y + (a).z*(b).z + (a).w*(b).w)

// ---------------------------------------------------------------------------
// prep: M = Wq @ Wk^T, r = bq @ Wk^T. bk dropped (softmax-invariant).
// ---------------------------------------------------------------------------
__global__ __launch_bounds__(256) void prep_kernel(
    const float* __restrict__ Wq, const float* __restrict__ Wk,
    const float* __restrict__ bq, float* __restrict__ Mmat,
    float* __restrict__ rvec)
{
    __shared__ float wq_s[32][65];
    __shared__ float wk_s[32][65];
    __shared__ float bq_s[64];
    const int t  = threadIdx.x;
    const int a0 = (int)(blockIdx.x >> 3) * 32;
    const int b0 = (int)(blockIdx.x & 7) * 32;
    const int ai = t >> 4;
    const int bj = t & 15;
    float acc00 = 0.f, acc01 = 0.f, acc10 = 0.f, acc11 = 0.f;
    float racc = 0.f;
    for (int z0 = 0; z0 < D; z0 += 64) {
        __syncthreads();
        #pragma unroll
        for (int i = 0; i < 2; ++i) {
            const int f4i = t + 256 * i;
            const int row = f4i >> 4;
            const int c   = (f4i & 15) * 4;
            float4 aa = *(const float4*)&Wq[(size_t)(a0 + row) * D + z0 + c];
            wq_s[row][c] = aa.x; wq_s[row][c+1] = aa.y; wq_s[row][c+2] = aa.z; wq_s[row][c+3] = aa.w;
            float4 bb = *(const float4*)&Wk[(size_t)(b0 + row) * D + z0 + c];
            wk_s[row][c] = bb.x; wk_s[row][c+1] = bb.y; wk_s[row][c+2] = bb.z; wk_s[row][c+3] = bb.w;
        }
        if (t < 64) bq_s[t] = bq[z0 + t];
        __syncthreads();
        #pragma unroll 8
        for (int z = 0; z < 64; ++z) {
            const float wq0 = wq_s[ai][z];
            const float wq1 = wq_s[ai + 16][z];
            const float wk0 = wk_s[bj][z];
            const float wk1 = wk_s[bj + 16][z];
            acc00 += wq0 * wk0; acc01 += wq0 * wk1;
            acc10 += wq1 * wk0; acc11 += wq1 * wk1;
        }
        if (a0 == 0 && t < 32) {
            #pragma unroll 8
            for (int z = 0; z < 64; ++z) racc += bq_s[z] * wk_s[t][z];
        }
    }
    Mmat[(size_t)(a0 + ai)      * D + b0 + bj]      = acc00;
    Mmat[(size_t)(a0 + ai)      * D + b0 + bj + 16] = acc01;
    Mmat[(size_t)(a0 + ai + 16) * D + b0 + bj]      = acc10;
    Mmat[(size_t)(a0 + ai + 16) * D + b0 + bj + 16] = acc11;
    if (a0 == 0 && t < 32) rvec[b0 + t] = racc;
}

// ---------------------------------------------------------------------------
// attn6 = R2 skeleton (in-kernel u; single launch; wall-best) + attn4's
// proven score phase (tree-reduce, transposed p_t, ballot mask) + attn4's
// v-split (wave w streams v rows [32w,32w+32) for ALL 4 queries; v read
// once per block) + normalized-p plain-sum cross-wave combine.
// M is L2-resident (256 KB, shared by all blocks) -> u phase loads are L2
// hits, unlike the latency-bound separate u_gemm (R7/R8 regression source).
// ---------------------------------------------------------------------------
__global__ __launch_bounds__(256) void attn6_kernel(
    const float* __restrict__ q, const float* __restrict__ k,
    const float* __restrict__ v, const int* __restrict__ m,
    const float* __restrict__ Mmat, const float* __restrict__ rvec,
    float* __restrict__ out)
{
    const int g    = blockIdx.x;
    const int t    = threadIdx.x;
    const int lane = t & 63;
    const int w    = t >> 6;     // wave id

    __shared__ float  q_s[4][D];          //  4 KB
    __shared__ float4 part_s[4][4][64];   // 16 KB (u partials, then v partials)
    __shared__ float4 u_s4[4][64];        //  4 KB
    __shared__ float  p_t[LKEYS][4];      //  2 KB [key][query]

    // ---- stage q + mask ballot for this wave's 32 keys ----
    {
        const float4* qg = (const float4*)(q + (size_t)g * 4 * D);
        ((float4*)q_s)[t] = qg[t];
    }
    const int mk = (lane < 32) ? m[(size_t)g * LKEYS + w * 32 + lane] : 0;
    const unsigned long long bal = __ballot(mk != 0);
    __syncthreads();

    // ---- u phase 1a: partials; wave w covers contraction dims [64w, 64w+64) ----
    {
        const float4* M4 = (const float4*)Mmat;
        float4 p0 = {0,0,0,0}, p1 = {0,0,0,0}, p2 = {0,0,0,0}, p3 = {0,0,0,0};
        const int base = w * 64;
        #pragma unroll 4
        for (int dd = 0; dd < 64; ++dd) {
            const int a = base + dd;
            const float4 m4 = M4[a * 64 + lane];        // L2-hit stream
            const float q0 = q_s[0][a], q1 = q_s[1][a], q2 = q_s[2][a], q3 = q_s[3][a];
            p0.x += q0*m4.x; p0.y += q0*m4.y; p0.z += q0*m4.z; p0.w += q0*m4.w;
            p1.x += q1*m4.x; p1.y += q1*m4.y; p1.z += q1*m4.z; p1.w += q1*m4.w;
            p2.x += q2*m4.x; p2.y += q2*m4.y; p2.z += q2*m4.z; p2.w += q2*m4.w;
            p3.x += q3*m4.x; p3.y += q3*m4.y; p3.z += q3*m4.z; p3.w += q3*m4.w;
        }
        part_s[w][0][lane] = p0; part_s[w][1][lane] = p1;
        part_s[w][2][lane] = p2; part_s[w][3][lane] = p3;
    }
    __syncthreads();

    // ---- u phase 1b: reduce; fold 1/sqrt(d_z) into u ----
    {
        float4 acc = ((const float4*)rvec)[lane];
        const float4 a0 = part_s[0][w][lane], a1 = part_s[1][w][lane];
        const float4 a2 = part_s[2][w][lane], a3 = part_s[3][w][lane];
        acc.x = (acc.x + a0.x + a1.x + a2.x + a3.x) * 0.0625f;
        acc.y = (acc.y + a0.y + a1.y + a2.y + a3.y) * 0.0625f;
        acc.z = (acc.z + a0.z + a1.z + a2.z + a3.z) * 0.0625f;
        acc.w = (acc.w + a0.w + a1.w + a2.w + a3.w) * 0.0625f;
        u_s4[w][lane] = acc;
    }
    __syncthreads();

    const float4 u0 = u_s4[0][lane], u1 = u_s4[1][lane];
    const float4 u2 = u_s4[2][lane], u3 = u_s4[3][lane];

    const float4* kg = (const float4*)(k + ((size_t)g * LKEYS + w * 32) * D);
    const float4* vg = (const float4*)(v + ((size_t)g * LKEYS + w * 32) * D);

    // ---- scores: wave's 32 keys, 8 batches of 4, batched tree-reduce ----
    #pragma unroll
    for (int it = 0; it < 8; ++it) {
        const int kb = it * 4;   // local key base
        const float4 ka0 = kg[(kb + 0) * 64 + lane];
        const float4 ka1 = kg[(kb + 1) * 64 + lane];
        const float4 ka2 = kg[(kb + 2) * 64 + lane];
        const float4 ka3 = kg[(kb + 3) * 64 + lane];

        float v16[16];   // v16[key*4 + q]
        v16[ 0]=DOT4(ka0,u0); v16[ 1]=DOT4(ka0,u1); v16[ 2]=DOT4(ka0,u2); v16[ 3]=DOT4(ka0,u3);
        v16[ 4]=DOT4(ka1,u0); v16[ 5]=DOT4(ka1,u1); v16[ 6]=DOT4(ka1,u2); v16[ 7]=DOT4(ka1,u3);
        v16[ 8]=DOT4(ka2,u0); v16[ 9]=DOT4(ka2,u1); v16[10]=DOT4(ka2,u2); v16[11]=DOT4(ka2,u3);
        v16[12]=DOT4(ka3,u0); v16[13]=DOT4(ka3,u1); v16[14]=DOT4(ka3,u2); v16[15]=DOT4(ka3,u3);

        // tree reduce across 64 lanes: 16 -> 8 -> 4 -> 2 -> 1 values/lane
        float v8[8];
        { const int hb = lane & 1;
          #pragma unroll
          for (int i = 0; i < 8; ++i) {
              const float keep = hb ? v16[8 + i] : v16[i];
              const float send = hb ? v16[i]     : v16[8 + i];
              v8[i] = keep + __shfl_xor(send, 1);
          } }
        float v4a[4];
        { const int hb = (lane >> 1) & 1;
          #pragma unroll
          for (int i = 0; i < 4; ++i) {
              const float keep = hb ? v8[4 + i] : v8[i];
              const float send = hb ? v8[i]     : v8[4 + i];
              v4a[i] = keep + __shfl_xor(send, 2);
          } }
        float v2a[2];
        { const int hb = (lane >> 2) & 1;
          #pragma unroll
          for (int i = 0; i < 2; ++i) {
              const float keep = hb ? v4a[2 + i] : v4a[i];
              const float send = hb ? v4a[i]     : v4a[2 + i];
              v2a[i] = keep + __shfl_xor(send, 4);
          } }
        float v1;
        { const int hb = (lane >> 3) & 1;
          const float keep = hb ? v2a[1] : v2a[0];
          const float send = hb ? v2a[0] : v2a[1];
          v1 = keep + __shfl_xor(send, 8); }
        v1 += __shfl_xor(v1, 16);
        v1 += __shfl_xor(v1, 32);

        if (lane < 16) {
            // lane bits -> value index i; i = local_key*4 + query
            const int i  = ((lane & 1) << 3) | ((lane & 2) << 1) | ((lane & 4) >> 1) | ((lane & 8) >> 3);
            const int kl = kb + (i >> 2);
            p_t[w * 32 + kl][i & 3] = ((bal >> kl) & 1ull) ? v1 : -1e30f;
        }
    }
    __syncthreads();

    // ---- softmax: wave w owns query w; write back NORMALIZED p ----
    {
        const float s0 = p_t[lane][w];
        const float s1 = p_t[lane + 64][w];
        float mx = fmaxf(s0, s1);
        #pragma unroll
        for (int off = 32; off > 0; off >>= 1) mx = fmaxf(mx, __shfl_xor(mx, off));
        const float e0 = __expf(s0 - mx);   // masked: exp(-huge) == 0 exactly
        const float e1 = __expf(s1 - mx);
        float su = e0 + e1;
        #pragma unroll
        for (int off = 32; off > 0; off >>= 1) su += __shfl_xor(su, off);
        const float inv = 1.0f / su;        // >=1 valid key guaranteed
        p_t[lane][w]      = e0 * inv;
        p_t[lane + 64][w] = e1 * inv;
    }
    __syncthreads();

    // ---- v phase: wave w streams v rows [32w,32w+32) for ALL 4 queries ----
    float4 a0 = {0,0,0,0}, a1 = {0,0,0,0}, a2 = {0,0,0,0}, a3 = {0,0,0,0};
    #pragma unroll
    for (int it = 0; it < 4; ++it) {
        const int base = it * 8;
        float4 va[8];
        #pragma unroll
        for (int j = 0; j < 8; ++j) va[j] = vg[(base + j) * 64 + lane];
        #pragma unroll
        for (int j = 0; j < 8; ++j) {
            const float4 pr = *(const float4*)&p_t[w * 32 + base + j][0];  // broadcast
            const float4 vv = va[j];
            a0.x += pr.x*vv.x; a0.y += pr.x*vv.y; a0.z += pr.x*vv.z; a0.w += pr.x*vv.w;
            a1.x += pr.y*vv.x; a1.y += pr.y*vv.y; a1.z += pr.y*vv.z; a1.w += pr.y*vv.w;
            a2.x += pr.z*vv.x; a2.y += pr.z*vv.y; a2.z += pr.z*vv.z; a2.w += pr.z*vv.w;
            a3.x += pr.w*vv.x; a3.y += pr.w*vv.y; a3.z += pr.w*vv.z; a3.w += pr.w*vv.w;
        }
    }

    // ---- cross-wave combine (p normalized -> plain sum) ----
    part_s[w][0][lane] = a0; part_s[w][1][lane] = a1;
    part_s[w][2][lane] = a2; part_s[w][3][lane] = a3;
    __syncthreads();
    {
        const float4 r0 = part_s[0][w][lane];
        const float4 r1 = part_s[1][w][lane];
        const float4 r2 = part_s[2][w][lane];
        const float4 r3 = part_s[3][w][lane];
        float4 o;
        o.x = r0.x + r1.x + r2.x + r3.x;
        o.y = r0.y + r1.y + r2.y + r3.y;
        o.z = r0.z + r1.z + r2.z + r3.z;
        o.w = r0.w + r1.w + r2.w + r3.w;
        ((float4*)(out + ((size_t)g * 4 + w) * D))[lane] = o;
    }
}

extern "C" void kernel_launch(void* const* d_in, const int* in_sizes, int n_in,
                              void* d_out, int out_size, void* d_ws, size_t ws_size,
                              hipStream_t stream) {
    // inputs: nq(0), q(1), k(2), v(3), m(4), Wq(5), bq(6), Wk(7), bk(8)
    const float* q  = (const float*)d_in[1];
    const float* k  = (const float*)d_in[2];
    const float* v  = (const float*)d_in[3];
    const int*   m  = (const int*)  d_in[4];
    const float* Wq = (const float*)d_in[5];
    const float* bq = (const float*)d_in[6];
    const float* Wk = (const float*)d_in[7];

    float* ws = (float*)d_ws;   // needs 257 KB only
    prep_kernel<<<64, 256, 0, stream>>>(Wq, Wk, bq, ws + MMAT_OFF, ws + RVEC_OFF);
    attn6_kernel<<<NGROUP, 256, 0, stream>>>(q, k, v, m, ws + MMAT_OFF, ws + RVEC_OFF,
                                             (float*)d_out);
}

// Round 10
// 68.509 us; speedup vs baseline: 1.5187x; 1.0139x over previous
//
#include <hip/hip_runtime.h>

#define D 256
#define LKEYS 128
#define NGROUP 1024

// ws layout (float offsets)
#define MMAT_OFF 0
#define RVEC_OFF (D * D)
#define WS_FLOATS (RVEC_OFF + D)            // 257 KB

#define DOT4(a, b) ((a).x*(b).x + (a).y*(b).y + (a).z*(b).z + (a).w*(b).w)

// ---------------------------------------------------------------------------
// prep: M = Wq @ Wk^T, r = bq @ Wk^T. bk dropped (softmax-invariant).
// ---------------------------------------------------------------------------
__global__ __launch_bounds__(256) void prep_kernel(
    const float* __restrict__ Wq, const float* __restrict__ Wk,
    const float* __restrict__ bq, float* __restrict__ Mmat,
    float* __restrict__ rvec)
{
    __shared__ float wq_s[32][65];
    __shared__ float wk_s[32][65];
    __shared__ float bq_s[64];
    const int t  = threadIdx.x;
    const int a0 = (int)(blockIdx.x >> 3) * 32;
    const int b0 = (int)(blockIdx.x & 7) * 32;
    const int ai = t >> 4;
    const int bj = t & 15;
    float acc00 = 0.f, acc01 = 0.f, acc10 = 0.f, acc11 = 0.f;
    float racc = 0.f;
    for (int z0 = 0; z0 < D; z0 += 64) {
        __syncthreads();
        #pragma unroll
        for (int i = 0; i < 2; ++i) {
            const int f4i = t + 256 * i;
            const int row = f4i >> 4;
            const int c   = (f4i & 15) * 4;
            float4 aa = *(const float4*)&Wq[(size_t)(a0 + row) * D + z0 + c];
            wq_s[row][c] = aa.x; wq_s[row][c+1] = aa.y; wq_s[row][c+2] = aa.z; wq_s[row][c+3] = aa.w;
            float4 bb = *(const float4*)&Wk[(size_t)(b0 + row) * D + z0 + c];
            wk_s[row][c] = bb.x; wk_s[row][c+1] = bb.y; wk_s[row][c+2] = bb.z; wk_s[row][c+3] = bb.w;
        }
        if (t < 64) bq_s[t] = bq[z0 + t];
        __syncthreads();
        #pragma unroll 8
        for (int z = 0; z < 64; ++z) {
            const float wq0 = wq_s[ai][z];
            const float wq1 = wq_s[ai + 16][z];
            const float wk0 = wk_s[bj][z];
            const float wk1 = wk_s[bj + 16][z];
            acc00 += wq0 * wk0; acc01 += wq0 * wk1;
            acc10 += wq1 * wk0; acc11 += wq1 * wk1;
        }
        if (a0 == 0 && t < 32) {
            #pragma unroll 8
            for (int z = 0; z < 64; ++z) racc += bq_s[z] * wk_s[t][z];
        }
    }
    Mmat[(size_t)(a0 + ai)      * D + b0 + bj]      = acc00;
    Mmat[(size_t)(a0 + ai)      * D + b0 + bj + 16] = acc01;
    Mmat[(size_t)(a0 + ai + 16) * D + b0 + bj]      = acc10;
    Mmat[(size_t)(a0 + ai + 16) * D + b0 + bj + 16] = acc11;
    if (a0 == 0 && t < 32) rvec[b0 + t] = racc;
}

// ---------------------------------------------------------------------------
// attn7 = attn6 (R9 winner) + per-block critical-path cuts:
//  (1) u-phase q_s reads as float4 (4x fewer DS broadcast reads), M unroll 8
//  (2) k batch-0 prefetched into VGPRs before the u phase
//  (3) v batch-0 prefetched into VGPRs before the softmax
//  (4) launch_bounds(256,4): VGPR cap 128 (grid caps CU at 4 blocks anyway)
// ---------------------------------------------------------------------------
__global__ __launch_bounds__(256, 4) void attn7_kernel(
    const float* __restrict__ q, const float* __restrict__ k,
    const float* __restrict__ v, const int* __restrict__ m,
    const float* __restrict__ Mmat, const float* __restrict__ rvec,
    float* __restrict__ out)
{
    const int g    = blockIdx.x;
    const int t    = threadIdx.x;
    const int lane = t & 63;
    const int w    = t >> 6;     // wave id

    __shared__ float  q_s[4][D];          //  4 KB
    __shared__ float4 part_s[4][4][64];   // 16 KB (u partials, then v partials)
    __shared__ float4 u_s4[4][64];        //  4 KB
    __shared__ float  p_t[LKEYS][4];      //  2 KB [key][query]

    const float4* kg = (const float4*)(k + ((size_t)g * LKEYS + w * 32) * D);
    const float4* vg = (const float4*)(v + ((size_t)g * LKEYS + w * 32) * D);

    // ---- stage q + mask ballot + k batch-0 prefetch (lands during u phase) ----
    {
        const float4* qg = (const float4*)(q + (size_t)g * 4 * D);
        ((float4*)q_s)[t] = qg[t];
    }
    const int mk = (lane < 32) ? m[(size_t)g * LKEYS + w * 32 + lane] : 0;
    const unsigned long long bal = __ballot(mk != 0);
    const float4 kp0 = kg[0 * 64 + lane];     // prefetch: first use after barrier
    const float4 kp1 = kg[1 * 64 + lane];
    const float4 kp2 = kg[2 * 64 + lane];
    const float4 kp3 = kg[3 * 64 + lane];
    __syncthreads();

    // ---- u phase 1a: partials; wave w covers dims [64w, 64w+64) ----
    {
        const float4* M4 = (const float4*)Mmat;
        float4 p0 = {0,0,0,0}, p1 = {0,0,0,0}, p2 = {0,0,0,0}, p3 = {0,0,0,0};
        const int base = w * 64;
        #pragma unroll 2
        for (int ch = 0; ch < 16; ++ch) {          // 4 dims per chunk
            const int a = base + ch * 4;
            const float4 qv0 = *(const float4*)&q_s[0][a];   // b128 broadcast
            const float4 qv1 = *(const float4*)&q_s[1][a];
            const float4 qv2 = *(const float4*)&q_s[2][a];
            const float4 qv3 = *(const float4*)&q_s[3][a];
            const float4 m40 = M4[(a + 0) * 64 + lane];      // L2-resident
            const float4 m41 = M4[(a + 1) * 64 + lane];
            const float4 m42 = M4[(a + 2) * 64 + lane];
            const float4 m43 = M4[(a + 3) * 64 + lane];
            p0.x += qv0.x*m40.x; p0.y += qv0.x*m40.y; p0.z += qv0.x*m40.z; p0.w += qv0.x*m40.w;
            p1.x += qv1.x*m40.x; p1.y += qv1.x*m40.y; p1.z += qv1.x*m40.z; p1.w += qv1.x*m40.w;
            p2.x += qv2.x*m40.x; p2.y += qv2.x*m40.y; p2.z += qv2.x*m40.z; p2.w += qv2.x*m40.w;
            p3.x += qv3.x*m40.x; p3.y += qv3.x*m40.y; p3.z += qv3.x*m40.z; p3.w += qv3.x*m40.w;
            p0.x += qv0.y*m41.x; p0.y += qv0.y*m41.y; p0.z += qv0.y*m41.z; p0.w += qv0.y*m41.w;
            p1.x += qv1.y*m41.x; p1.y += qv1.y*m41.y; p1.z += qv1.y*m41.z; p1.w += qv1.y*m41.w;
            p2.x += qv2.y*m41.x; p2.y += qv2.y*m41.y; p2.z += qv2.y*m41.z; p2.w += qv2.y*m41.w;
            p3.x += qv3.y*m41.x; p3.y += qv3.y*m41.y; p3.z += qv3.y*m41.z; p3.w += qv3.y*m41.w;
            p0.x += qv0.z*m42.x; p0.y += qv0.z*m42.y; p0.z += qv0.z*m42.z; p0.w += qv0.z*m42.w;
            p1.x += qv1.z*m42.x; p1.y += qv1.z*m42.y; p1.z += qv1.z*m42.z; p1.w += qv1.z*m42.w;
            p2.x += qv2.z*m42.x; p2.y += qv2.z*m42.y; p2.z += qv2.z*m42.z; p2.w += qv2.z*m42.w;
            p3.x += qv3.z*m42.x; p3.y += qv3.z*m42.y; p3.z += qv3.z*m42.z; p3.w += qv3.z*m42.w;
            p0.x += qv0.w*m43.x; p0.y += qv0.w*m43.y; p0.z += qv0.w*m43.z; p0.w += qv0.w*m43.w;
            p1.x += qv1.w*m43.x; p1.y += qv1.w*m43.y; p1.z += qv1.w*m43.z; p1.w += qv1.w*m43.w;
            p2.x += qv2.w*m43.x; p2.y += qv2.w*m43.y; p2.z += qv2.w*m43.z; p2.w += qv2.w*m43.w;
            p3.x += qv3.w*m43.x; p3.y += qv3.w*m43.y; p3.z += qv3.w*m43.z; p3.w += qv3.w*m43.w;
        }
        part_s[w][0][lane] = p0; part_s[w][1][lane] = p1;
        part_s[w][2][lane] = p2; part_s[w][3][lane] = p3;
    }
    __syncthreads();

    // ---- u phase 1b: reduce; fold 1/sqrt(d_z) into u ----
    {
        float4 acc = ((const float4*)rvec)[lane];
        const float4 a0 = part_s[0][w][lane], a1 = part_s[1][w][lane];
        const float4 a2 = part_s[2][w][lane], a3 = part_s[3][w][lane];
        acc.x = (acc.x + a0.x + a1.x + a2.x + a3.x) * 0.0625f;
        acc.y = (acc.y + a0.y + a1.y + a2.y + a3.y) * 0.0625f;
        acc.z = (acc.z + a0.z + a1.z + a2.z + a3.z) * 0.0625f;
        acc.w = (acc.w + a0.w + a1.w + a2.w + a3.w) * 0.0625f;
        u_s4[w][lane] = acc;
    }
    __syncthreads();

    const float4 u0 = u_s4[0][lane], u1 = u_s4[1][lane];
    const float4 u2 = u_s4[2][lane], u3 = u_s4[3][lane];

    // ---- scores: wave's 32 keys, 8 batches of 4, batched tree-reduce ----
    #pragma unroll
    for (int it = 0; it < 8; ++it) {
        const int kb = it * 4;   // local key base
        const float4 ka0 = (it == 0) ? kp0 : kg[(kb + 0) * 64 + lane];
        const float4 ka1 = (it == 0) ? kp1 : kg[(kb + 1) * 64 + lane];
        const float4 ka2 = (it == 0) ? kp2 : kg[(kb + 2) * 64 + lane];
        const float4 ka3 = (it == 0) ? kp3 : kg[(kb + 3) * 64 + lane];

        float v16[16];   // v16[key*4 + q]
        v16[ 0]=DOT4(ka0,u0); v16[ 1]=DOT4(ka0,u1); v16[ 2]=DOT4(ka0,u2); v16[ 3]=DOT4(ka0,u3);
        v16[ 4]=DOT4(ka1,u0); v16[ 5]=DOT4(ka1,u1); v16[ 6]=DOT4(ka1,u2); v16[ 7]=DOT4(ka1,u3);
        v16[ 8]=DOT4(ka2,u0); v16[ 9]=DOT4(ka2,u1); v16[10]=DOT4(ka2,u2); v16[11]=DOT4(ka2,u3);
        v16[12]=DOT4(ka3,u0); v16[13]=DOT4(ka3,u1); v16[14]=DOT4(ka3,u2); v16[15]=DOT4(ka3,u3);

        // tree reduce across 64 lanes: 16 -> 8 -> 4 -> 2 -> 1 values/lane
        float v8[8];
        { const int hb = lane & 1;
          #pragma unroll
          for (int i = 0; i < 8; ++i) {
              const float keep = hb ? v16[8 + i] : v16[i];
              const float send = hb ? v16[i]     : v16[8 + i];
              v8[i] = keep + __shfl_xor(send, 1);
          } }
        float v4a[4];
        { const int hb = (lane >> 1) & 1;
          #pragma unroll
          for (int i = 0; i < 4; ++i) {
              const float keep = hb ? v8[4 + i] : v8[i];
              const float send = hb ? v8[i]     : v8[4 + i];
              v4a[i] = keep + __shfl_xor(send, 2);
          } }
        float v2a[2];
        { const int hb = (lane >> 2) & 1;
          #pragma unroll
          for (int i = 0; i < 2; ++i) {
              const float keep = hb ? v4a[2 + i] : v4a[i];
              const float send = hb ? v4a[i]     : v4a[2 + i];
              v2a[i] = keep + __shfl_xor(send, 4);
          } }
        float v1;
        { const int hb = (lane >> 3) & 1;
          const float keep = hb ? v2a[1] : v2a[0];
          const float send = hb ? v2a[0] : v2a[1];
          v1 = keep + __shfl_xor(send, 8); }
        v1 += __shfl_xor(v1, 16);
        v1 += __shfl_xor(v1, 32);

        if (lane < 16) {
            // lane bits -> value index i; i = local_key*4 + query
            const int i  = ((lane & 1) << 3) | ((lane & 2) << 1) | ((lane & 4) >> 1) | ((lane & 8) >> 3);
            const int kl = kb + (i >> 2);
            p_t[w * 32 + kl][i & 3] = ((bal >> kl) & 1ull) ? v1 : -1e30f;
        }
    }
    __syncthreads();

    // ---- v batch-0 prefetch (lands during softmax) ----
    float4 vp[8];
    #pragma unroll
    for (int j = 0; j < 8; ++j) vp[j] = vg[j * 64 + lane];

    // ---- softmax: wave w owns query w; write back NORMALIZED p ----
    {
        const float s0 = p_t[lane][w];
        const float s1 = p_t[lane + 64][w];
        float mx = fmaxf(s0, s1);
        #pragma unroll
        for (int off = 32; off > 0; off >>= 1) mx = fmaxf(mx, __shfl_xor(mx, off));
        const float e0 = __expf(s0 - mx);   // masked: exp(-huge) == 0 exactly
        const float e1 = __expf(s1 - mx);
        float su = e0 + e1;
        #pragma unroll
        for (int off = 32; off > 0; off >>= 1) su += __shfl_xor(su, off);
        const float inv = 1.0f / su;        // >=1 valid key guaranteed
        p_t[lane][w]      = e0 * inv;
        p_t[lane + 64][w] = e1 * inv;
    }
    __syncthreads();

    // ---- v phase: wave w streams v rows [32w,32w+32) for ALL 4 queries ----
    float4 a0 = {0,0,0,0}, a1 = {0,0,0,0}, a2 = {0,0,0,0}, a3 = {0,0,0,0};
    #pragma unroll
    for (int it = 0; it < 4; ++it) {
        const int base = it * 8;
        float4 va[8];
        if (it == 0) {
            #pragma unroll
            for (int j = 0; j < 8; ++j) va[j] = vp[j];
        } else {
            #pragma unroll
            for (int j = 0; j < 8; ++j) va[j] = vg[(base + j) * 64 + lane];
        }
        #pragma unroll
        for (int j = 0; j < 8; ++j) {
            const float4 pr = *(const float4*)&p_t[w * 32 + base + j][0];  // broadcast
            const float4 vv = va[j];
            a0.x += pr.x*vv.x; a0.y += pr.x*vv.y; a0.z += pr.x*vv.z; a0.w += pr.x*vv.w;
            a1.x += pr.y*vv.x; a1.y += pr.y*vv.y; a1.z += pr.y*vv.z; a1.w += pr.y*vv.w;
            a2.x += pr.z*vv.x; a2.y += pr.z*vv.y; a2.z += pr.z*vv.z; a2.w += pr.z*vv.w;
            a3.x += pr.w*vv.x; a3.y += pr.w*vv.y; a3.z += pr.w*vv.z; a3.w += pr.w*vv.w;
        }
    }

    // ---- cross-wave combine (p normalized -> plain sum) ----
    part_s[w][0][lane] = a0; part_s[w][1][lane] = a1;
    part_s[w][2][lane] = a2; part_s[w][3][lane] = a3;
    __syncthreads();
    {
        const float4 r0 = part_s[0][w][lane];
        const float4 r1 = part_s[1][w][lane];
        const float4 r2 = part_s[2][w][lane];
        const float4 r3 = part_s[3][w][lane];
        float4 o;
        o.x = r0.x + r1.x + r2.x + r3.x;
        o.y = r0.y + r1.y + r2.y + r3.y;
        o.z = r0.z + r1.z + r2.z + r3.z;
        o.w = r0.w + r1.w + r2.w + r3.w;
        ((float4*)(out + ((size_t)g * 4 + w) * D))[lane] = o;
    }
}

extern "C" void kernel_launch(void* const* d_in, const int* in_sizes, int n_in,
                              void* d_out, int out_size, void* d_ws, size_t ws_size,
                              hipStream_t stream) {
    // inputs: nq(0), q(1), k(2), v(3), m(4), Wq(5), bq(6), Wk(7), bk(8)
    const float* q  = (const float*)d_in[1];
    const float* k  = (const float*)d_in[2];
    const float* v  = (const float*)d_in[3];
    const int*   m  = (const int*)  d_in[4];
    const float* Wq = (const float*)d_in[5];
    const float* bq = (const float*)d_in[6];
    const float* Wk = (const float*)d_in[7];

    float* ws = (float*)d_ws;   // needs 257 KB only
    prep_kernel<<<64, 256, 0, stream>>>(Wq, Wk, bq, ws + MMAT_OFF, ws + RVEC_OFF);
    attn7_kernel<<<NGROUP, 256, 0, stream>>>(q, k, v, m, ws + MMAT_OFF, ws + RVEC_OFF,
                                             (float*)d_out);
}